// Round 14
// baseline (82.091 us; speedup 1.0000x reference)
//
#include <hip/hip_runtime.h>
#include <hip/hip_bf16.h>

#define CIN  64
#define HH   128
#define WW   128
#define COUT 128
#define HO   126
#define WO   126
#define NB   32
#define HW   (HH * WW)

typedef __bf16 bf16x8 __attribute__((ext_vector_type(8)));
typedef float f32x16 __attribute__((ext_vector_type(16)));

// ws2 granule layout: [step(18)=(s,h)][kg(4)][cout(128)] 16B granules
// granule(step,kg,cout)[j] = bf16(w[cout][ci = 32h + 8kg + j][s])
__global__ void wreorder_3556(const float* __restrict__ w, unsigned short* __restrict__ ws2) {
    int e = blockIdx.x * 256 + threadIdx.x;      // 0..73727
    if (e >= 73728) return;
    int j = e & 7, cout = (e >> 3) & 127, kg = (e >> 10) & 3, h = (e >> 12) & 1, s = e >> 13;
    __bf16 v = (__bf16)w[cout * 576 + (h * 32 + kg * 8 + j) * 9 + s];
    ws2[e] = __builtin_bit_cast(unsigned short, v);
}

// LDS: xs [row(6)][cg(8)][col(130)] 16B granules (ci-major) @0 = 99840 | pmin[8][128] f32
#define XS_OFF  0
#define PM_OFF  99840
#define SMEM_BYTES (99840 + 8 * 128 * 4)   // 103936 -> 1 block/CU, 8 waves

__device__ __forceinline__ unsigned lds_addr(const void* p) {
    return (unsigned)(unsigned long long)(const __attribute__((address_space(3))) unsigned char*)p;
}
template<int OFF>
__device__ __forceinline__ bf16x8 ds_read128(unsigned base) {
    bf16x8 d;
    asm volatile("ds_read_b128 %0, %1 offset:%c2" : "=v"(d) : "v"(base), "i"(OFF));
    return d;
}
template<int OFF>
__device__ __forceinline__ bf16x8 glob_load128(const unsigned char* sbase, unsigned voff) {
    bf16x8 d;
    asm volatile("global_load_dwordx4 %0, %1, %2 offset:%c3"
                 : "=v"(d) : "v"(voff), "s"(sbase), "i"(OFF));
    return d;
}

#define MFMA_(a, b, c) __builtin_amdgcn_mfma_f32_32x32x16_bf16((a), (b), (c), 0, 0, 0)

// step T: s = T>>1, h = T&1; kh = s/3, kw = s%3
#define S_(T)  ((T) >> 1)
#define H_(T)  ((T) & 1)
#define KH_(T) (S_(T) / 3)
#define KW_(T) (S_(T) % 3)
#define IMMB(T, KS, N) (KH_(T) * 16640 + (H_(T) * 4 + (KS) * 2) * 2080 + ((N) * 32 + KW_(T)) * 16)

template<bool USE_WS>
__global__ __launch_bounds__(512, 2)
void conv_min_tanh_3556(const float* __restrict__ x, const float* __restrict__ w,
                        const float* __restrict__ bias,
                        const unsigned char* __restrict__ wsr_b,
                        float* __restrict__ out) {
    __shared__ __align__(16) unsigned char smem[SMEM_BYTES];
    float* pmin = (float*)(smem + PM_OFF);

    // XCD-chunked bijective swizzle (1024 = 8 * 128)
    const int bid = blockIdx.x;
    const int blk = (bid & 7) * 128 + (bid >> 3);
    const int b   = blk >> 5;                 // batch
    const int R   = (blk & 31) * 4;           // output rows R..R+3 (last block ragged)

    const int tid  = threadIdx.x;
    const int lane = tid & 63;
    const int wid  = tid >> 6;                // 0..7
    const int l31 = lane & 31;
    const int l5  = lane >> 5;
    const int waveM = wid & 1;                // cout half
    const int waveR = wid >> 1;               // output row 0..3 within block
    const int mb = waveM * 64;

    // ---- stage x rows R..R+5 (row-clamped) into xs[row][cg][col] granules
    {
        const int cg = tid >> 6, c0 = tid & 63;
        const float* xb0 = x + (size_t)b * CIN * HW + (size_t)(cg * 8) * HW;
        #pragma unroll
        for (int row = 0; row < 6; ++row) {
            int rr = R + row; if (rr > 127) rr = 127;   // clamp (values unused for ragged tail)
            #pragma unroll
            for (int i = 0; i < 2; ++i) {
                const float* src = xb0 + (size_t)rr * WW + i * 64 + c0;
                union { unsigned short us[8]; int4 i4; } p;
                #pragma unroll
                for (int j = 0; j < 8; ++j) {
                    __bf16 t = (__bf16)src[(size_t)j * HW];
                    p.us[j] = __builtin_bit_cast(unsigned short, t);
                }
                *(int4*)(smem + XS_OFF + ((row * 8 + cg) * 130 + i * 64 + c0) * 16) = p.i4;
            }
        }
        if (tid < 96) {   // zero-pad cols 128,129 for all 6 rows
            int row = tid >> 4, cgz = (tid >> 1) & 7, colz = 128 + (tid & 1);
            int4 z = {0, 0, 0, 0};
            *(int4*)(smem + XS_OFF + ((row * 8 + cgz) * 130 + colz) * 16) = z;
        }
    }
    __syncthreads();

    f32x16 acc[2][4] = {};   // [m][n] : 64 cout x 128 col

    if constexpr (USE_WS) {
        const unsigned baseB = lds_addr(smem) + (unsigned)(waveR * 16640 + l5 * 2080 + l31 * 16);
        const unsigned voffA = (unsigned)(l5 * 2048 + (mb + l31) * 16);

        bf16x8 A3[3][2][2];   // [slot(3)][ks][m]
        bf16x8 B2[2][2][4];   // [slot(2)][ks][n]

        #define PRELA(T) do { const unsigned _va = voffA + (T) * 8192u, _vb = _va + 4096u;   \
            A3[(T) % 3][0][0] = glob_load128<0>(wsr_b, _va);                                  \
            A3[(T) % 3][0][1] = glob_load128<512>(wsr_b, _va);                                \
            A3[(T) % 3][1][0] = glob_load128<0>(wsr_b, _vb);                                  \
            A3[(T) % 3][1][1] = glob_load128<512>(wsr_b, _vb); } while (0)

        #define PRELB(T) do {                                                                 \
            B2[(T) & 1][0][0] = ds_read128<IMMB(T,0,0)>(baseB);                               \
            B2[(T) & 1][0][1] = ds_read128<IMMB(T,0,1)>(baseB);                               \
            B2[(T) & 1][0][2] = ds_read128<IMMB(T,0,2)>(baseB);                               \
            B2[(T) & 1][0][3] = ds_read128<IMMB(T,0,3)>(baseB);                               \
            B2[(T) & 1][1][0] = ds_read128<IMMB(T,1,0)>(baseB);                               \
            B2[(T) & 1][1][1] = ds_read128<IMMB(T,1,1)>(baseB);                               \
            B2[(T) & 1][1][2] = ds_read128<IMMB(T,1,2)>(baseB);                               \
            B2[(T) & 1][1][3] = ds_read128<IMMB(T,1,3)>(baseB); } while (0)

        #define KSTEP(T) do {                                                                 \
            if ((T) <= 15)      asm volatile("s_waitcnt lgkmcnt(8) vmcnt(8)" ::: "memory");   \
            else if ((T) == 16) asm volatile("s_waitcnt lgkmcnt(8) vmcnt(4)" ::: "memory");   \
            else                asm volatile("s_waitcnt lgkmcnt(0) vmcnt(0)" ::: "memory");   \
            __builtin_amdgcn_sched_barrier(0);                                                \
            __builtin_amdgcn_s_setprio(1);                                                    \
            { const int _q = (T) & 1, _p = (T) % 3;                                           \
              acc[0][0] = MFMA_(A3[_p][0][0], B2[_q][0][0], acc[0][0]);                       \
              acc[0][1] = MFMA_(A3[_p][0][0], B2[_q][0][1], acc[0][1]);                       \
              acc[0][2] = MFMA_(A3[_p][0][0], B2[_q][0][2], acc[0][2]);                       \
              acc[0][3] = MFMA_(A3[_p][0][0], B2[_q][0][3], acc[0][3]);                       \
              acc[1][0] = MFMA_(A3[_p][0][1], B2[_q][0][0], acc[1][0]);                       \
              acc[1][1] = MFMA_(A3[_p][0][1], B2[_q][0][1], acc[1][1]);                       \
              acc[1][2] = MFMA_(A3[_p][0][1], B2[_q][0][2], acc[1][2]);                       \
              acc[1][3] = MFMA_(A3[_p][0][1], B2[_q][0][3], acc[1][3]);                       \
              acc[0][0] = MFMA_(A3[_p][1][0], B2[_q][1][0], acc[0][0]);                       \
              acc[0][1] = MFMA_(A3[_p][1][0], B2[_q][1][1], acc[0][1]);                       \
              acc[0][2] = MFMA_(A3[_p][1][0], B2[_q][1][2], acc[0][2]);                       \
              acc[0][3] = MFMA_(A3[_p][1][0], B2[_q][1][3], acc[0][3]);                       \
              acc[1][0] = MFMA_(A3[_p][1][1], B2[_q][1][0], acc[1][0]);                       \
              acc[1][1] = MFMA_(A3[_p][1][1], B2[_q][1][1], acc[1][1]);                       \
              acc[1][2] = MFMA_(A3[_p][1][1], B2[_q][1][2], acc[1][2]);                       \
              acc[1][3] = MFMA_(A3[_p][1][1], B2[_q][1][3], acc[1][3]); }                     \
            __builtin_amdgcn_s_setprio(0);                                                    \
            __builtin_amdgcn_sched_barrier(0);                                                \
            if ((T) + 2 <= 17) { PRELB((T) + 2); }                                            \
            if ((T) + 3 <= 17) { PRELA((T) + 3); }                                            \
        } while (0)

        PRELA(0); PRELB(0); PRELA(1); PRELB(1); PRELA(2);

        KSTEP(0);  KSTEP(1);  KSTEP(2);  KSTEP(3);  KSTEP(4);  KSTEP(5);
        KSTEP(6);  KSTEP(7);  KSTEP(8);  KSTEP(9);  KSTEP(10); KSTEP(11);
        KSTEP(12); KSTEP(13); KSTEP(14); KSTEP(15); KSTEP(16); KSTEP(17);

        asm volatile("s_waitcnt lgkmcnt(0) vmcnt(0)" ::: "memory");
        __builtin_amdgcn_sched_barrier(0);
    } else {
        // fallback: plain loop straight from w
        #pragma unroll
        for (int step = 0; step < 18; ++step) {
            const int s = step >> 1, h = step & 1;
            const int kh = s / 3, kw = s % 3;
            bf16x8 A[2][2], B[2][4];
            #pragma unroll
            for (int ks = 0; ks < 2; ++ks) {
                #pragma unroll
                for (int j = 0; j < 8; ++j) {
                    A[ks][0][j] = (__bf16)w[(mb + l31) * 576 + (h * 32 + (2 * ks + l5) * 8 + j) * 9 + s];
                    A[ks][1][j] = (__bf16)w[(mb + 32 + l31) * 576 + (h * 32 + (2 * ks + l5) * 8 + j) * 9 + s];
                }
                const int rowOff = ((waveR + kh) * 8 + h * 4 + ks * 2 + l5) * 2080;
                #pragma unroll
                for (int n = 0; n < 4; ++n)
                    B[ks][n] = *(const bf16x8*)(smem + XS_OFF + rowOff + (n * 32 + l31 + kw) * 16);
            }
            #pragma unroll
            for (int ks = 0; ks < 2; ++ks)
                #pragma unroll
                for (int m = 0; m < 2; ++m)
                    #pragma unroll
                    for (int n = 0; n < 4; ++n)
                        acc[m][n] = MFMA_(A[ks][m], B[ks][n], acc[m][n]);
        }
    }

    // ---- epilogue: +bias, min over couts, cross-lane, cross-wave, tanh(tanh)
    float pm[4] = {1e30f, 1e30f, 1e30f, 1e30f};
    #pragma unroll
    for (int m = 0; m < 2; ++m) {
        #pragma unroll
        for (int r = 0; r < 16; ++r) {
            float bv = bias[mb + m * 32 + (r & 3) + 8 * (r >> 2) + 4 * l5];
            #pragma unroll
            for (int n = 0; n < 4; ++n)
                pm[n] = fminf(pm[n], acc[m][n][r] + bv);
        }
    }
    #pragma unroll
    for (int n = 0; n < 4; ++n)
        pm[n] = fminf(pm[n], __shfl_xor(pm[n], 32, 64));
    if (l5 == 0) {
        #pragma unroll
        for (int n = 0; n < 4; ++n)
            pmin[(waveR * 2 + waveM) * 128 + n * 32 + l31] = pm[n];
    }
    __syncthreads();

    {
        const int hh  = tid >> 7;            // 0..3
        const int col = tid & 127;
        const int orow = R + hh;
        if (col < WO && orow < HO) {
            float v = fminf(pmin[(hh * 2 + 0) * 128 + col], pmin[(hh * 2 + 1) * 128 + col]);
            v = tanhf(tanhf(v));
            out[((size_t)b * HO + orow) * WO + col] = v;
        }
    }
}

extern "C" void kernel_launch(void* const* d_in, const int* in_sizes, int n_in,
                              void* d_out, int out_size, void* d_ws, size_t ws_size,
                              hipStream_t stream) {
    const float* x    = (const float*)d_in[0];
    const float* w    = (const float*)d_in[1];
    const float* bias = (const float*)d_in[2];
    float* out = (float*)d_out;

    const size_t ws_needed = (size_t)18 * 4 * 128 * 16;   // 147456 B
    if (ws_size >= ws_needed) {
        unsigned short* wsb = (unsigned short*)d_ws;
        wreorder_3556<<<288, 256, 0, stream>>>(w, wsb);
        conv_min_tanh_3556<true><<<NB * 32, 512, 0, stream>>>(x, w, bias, (const unsigned char*)wsb, out);
    } else {
        conv_min_tanh_3556<false><<<NB * 32, 512, 0, stream>>>(x, w, bias, nullptr, out);
    }
}